// Round 2
// baseline (37451.938 us; speedup 1.0000x reference)
//
#include <hip/hip_runtime.h>

// Problem constants: B=64, T=512, IN=256, H=1024, L=2, OUT=128
#define B_ 64
#define T_ 512
#define IN_ 256
#define H_ 1024
#define OUT_ 128
#define NBLK 256

// ---------------------------------------------------------------------------
// Grid barrier for a co-resident (cooperative) launch.
// Release fence (wbL2) before arrival makes h-writes visible at the MALL;
// acquire fence (buffer_inv) after release makes every CU's L1/L2 drop stale
// copies of re-read buffers (h1 ping-pong, ys rows). Weights live in LDS, so
// the per-step L2 invalidation costs ~nothing.
// ---------------------------------------------------------------------------
__device__ __forceinline__ void grid_barrier(unsigned* bar, unsigned nblk) {
  __syncthreads();
  if (threadIdx.x == 0) {
    __builtin_amdgcn_fence(__ATOMIC_RELEASE, "agent");
    unsigned g = __hip_atomic_load(bar + 1, __ATOMIC_RELAXED, __HIP_MEMORY_SCOPE_AGENT);
    unsigned arrived =
        __hip_atomic_fetch_add(bar, 1u, __ATOMIC_RELAXED, __HIP_MEMORY_SCOPE_AGENT) + 1u;
    if (arrived == nblk) {
      __hip_atomic_store(bar, 0u, __ATOMIC_RELAXED, __HIP_MEMORY_SCOPE_AGENT);
      __hip_atomic_fetch_add(bar + 1, 1u, __ATOMIC_RELEASE, __HIP_MEMORY_SCOPE_AGENT);
    } else {
      while (__hip_atomic_load(bar + 1, __ATOMIC_RELAXED, __HIP_MEMORY_SCOPE_AGENT) == g) {
        __builtin_amdgcn_s_sleep(1);
      }
    }
    __builtin_amdgcn_fence(__ATOMIC_ACQUIRE, "agent");
  }
  __syncthreads();
}

// dot of 1024 floats: g = global row (16B aligned), l = (LDS) weight row with
// XOR swizzle sw applied to the float index (sw = 0 for plain rows).
__device__ __forceinline__ float dot1024(const float* __restrict__ g,
                                         const float* __restrict__ l, int sw) {
  float s0 = 0.f, s1 = 0.f, s2 = 0.f, s3 = 0.f;
#pragma unroll 2
  for (int k = 0; k < 1024; k += 16) {
    float4 a0 = *(const float4*)(g + k + 0);
    float4 a1 = *(const float4*)(g + k + 4);
    float4 a2 = *(const float4*)(g + k + 8);
    float4 a3 = *(const float4*)(g + k + 12);
    float4 w0 = *(const float4*)(l + ((k + 0) ^ sw));
    float4 w1 = *(const float4*)(l + ((k + 4) ^ sw));
    float4 w2 = *(const float4*)(l + ((k + 8) ^ sw));
    float4 w3 = *(const float4*)(l + ((k + 12) ^ sw));
    s0 += a0.x * w0.x + a0.y * w0.y + a0.z * w0.z + a0.w * w0.w;
    s1 += a1.x * w1.x + a1.y * w1.y + a1.z * w1.z + a1.w * w1.w;
    s2 += a2.x * w2.x + a2.y * w2.y + a2.z * w2.z + a2.w * w2.w;
    s3 += a3.x * w3.x + a3.y * w3.y + a3.z * w3.z + a3.w * w3.w;
  }
  return (s0 + s1) + (s2 + s3);
}

// ---------------------------------------------------------------------------
// Kernel 1: xw0[t][b][:] = x[b][t][:] @ W_ih0^T + (b_ih0 + b_hh0)
// M = T*B = 32768 (row r = t*64 + b), N = 1024, K = 256. Plain fp32 tile GEMM.
// grid: (16 col-tiles, 512 t), block 256, 64x64 tile, 4x4 per thread.
// ---------------------------------------------------------------------------
__global__ __launch_bounds__(256) void xw0_gemm(const float* __restrict__ x,
                                                const float* __restrict__ W,
                                                const float* __restrict__ bih,
                                                const float* __restrict__ bhh,
                                                float* __restrict__ xw) {
  __shared__ float As[64][65];
  __shared__ float Bs[64][65];
  const int t = blockIdx.y;
  const int j0 = blockIdx.x * 64;
  const int tid = threadIdx.x;
  const int tb = (tid & 15) * 4;  // A-row (b) base for compute
  const int tj = (tid >> 4) * 4;  // B-row (j) base for compute
  float acc[4][4] = {};

  for (int kt = 0; kt < 256; kt += 64) {
    const int lr = tid >> 4;          // 0..15 load row
    const int kq = (tid & 15) * 4;    // 0..60 load col (float4)
#pragma unroll
    for (int p = 0; p < 4; ++p) {
      int r = lr + p * 16;  // 0..63
      float4 va = *(const float4*)(x + (r * T_ + t) * IN_ + kt + kq);
      As[r][kq + 0] = va.x; As[r][kq + 1] = va.y;
      As[r][kq + 2] = va.z; As[r][kq + 3] = va.w;
      float4 vb = *(const float4*)(W + (j0 + r) * IN_ + kt + kq);
      Bs[r][kq + 0] = vb.x; Bs[r][kq + 1] = vb.y;
      Bs[r][kq + 2] = vb.z; Bs[r][kq + 3] = vb.w;
    }
    __syncthreads();
#pragma unroll 4
    for (int k = 0; k < 64; ++k) {
      float a0 = As[tb + 0][k], a1 = As[tb + 1][k], a2 = As[tb + 2][k], a3 = As[tb + 3][k];
      float b0 = Bs[tj + 0][k], b1 = Bs[tj + 1][k], b2 = Bs[tj + 2][k], b3 = Bs[tj + 3][k];
      acc[0][0] += a0 * b0; acc[0][1] += a0 * b1; acc[0][2] += a0 * b2; acc[0][3] += a0 * b3;
      acc[1][0] += a1 * b0; acc[1][1] += a1 * b1; acc[1][2] += a1 * b2; acc[1][3] += a1 * b3;
      acc[2][0] += a2 * b0; acc[2][1] += a2 * b1; acc[2][2] += a2 * b2; acc[2][3] += a2 * b3;
      acc[3][0] += a3 * b0; acc[3][1] += a3 * b1; acc[3][2] += a3 * b2; acc[3][3] += a3 * b3;
    }
    __syncthreads();
  }

  const int row0 = t * B_;
#pragma unroll
  for (int i = 0; i < 4; ++i) {
    int b = tb + i;
#pragma unroll
    for (int jj = 0; jj < 4; ++jj) {
      int col = j0 + tj + jj;
      acc[i][jj] += bih[col] + bhh[col];
    }
    float4 v = make_float4(acc[i][0], acc[i][1], acc[i][2], acc[i][3]);
    *(float4*)(xw + (row0 + b) * H_ + j0 + tj) = v;
  }
}

// ---------------------------------------------------------------------------
// Kernel 2: persistent cooperative kernel.
//   phase 0: stage W_hh0 16-row slice into LDS; ys[0] = tanh(xw0[0])
//   layer 0: t = 1..511: ys[t] = tanh(xw0[t] + ys[t-1] @ W_hh0^T)   (in place)
//   restage: [W_ih1 | W_hh1] 16-row slice into LDS (128 KiB dynamic)
//   layer 1: t = 0..511: h1 = tanh(b1 + ys[t]@W_ih1^T + h1prev@W_hh1^T)
//            ping-pong h1a/h1b (t even -> h1a, odd -> h1b; t=511 -> h1b)
//   final:   out = sigmoid([ys[511], h1b] @ W_lin^T + b_lin)
// grid 256 blocks x 256 threads, 1 block/CU. Block owns 16 b x 16 j outputs.
// ---------------------------------------------------------------------------
__global__ __launch_bounds__(256, 1) void rnn_seq(
    const float* __restrict__ Whh0, const float* __restrict__ Wih1,
    const float* __restrict__ Whh1, const float* __restrict__ bih1,
    const float* __restrict__ bhh1, const float* __restrict__ Wlin,
    const float* __restrict__ blin, float* __restrict__ ys, float* __restrict__ h1a,
    float* __restrict__ h1b, unsigned* __restrict__ bar, float* __restrict__ out) {
  extern __shared__ float lds[];  // 16*2048 floats = 128 KiB
  const int tid = threadIdx.x;
  const int blk = blockIdx.x;
  // XCD-aware decomposition: blocks on one XCD share 8 consecutive j-groups,
  // so each XCD's L2 only streams its own h rows within a step.
  const int xcd = blk & 7;
  const int idx = blk >> 3;
  const int jg = xcd * 8 + (idx & 7);  // 0..63 -> 16 output columns
  const int bg = idx >> 3;             // 0..3  -> 16 batch rows
  const int jl = tid & 15;
  const int bl = tid >> 4;
  const int b = bg * 16 + bl;
  const int j = jg * 16 + jl;
  const int sw = (jl & 7) << 2;  // LDS XOR swizzle for this thread's W row

  // ---- phase 0: stage Whh0 slice (16 x 1024), tanh on ys[0]
  for (int i4 = tid * 4; i4 < 16 * 1024; i4 += 256 * 4) {
    int r = i4 >> 10, k = i4 & 1023;
    float4 v = *(const float4*)(Whh0 + (jg * 16 + r) * H_ + k);
    *(float4*)(lds + r * 1024 + (k ^ ((r & 7) << 2))) = v;
  }
  {
    int i = blk * 256 + tid;  // exactly covers 64*1024
    ys[i] = tanhf(ys[i]);
  }
  grid_barrier(bar, NBLK);

  // ---- layer 0 recurrence (in place over ys)
  const float* wl0 = lds + jl * 1024;
  for (int t = 1; t < T_; ++t) {
    const float* hrow = ys + ((t - 1) * B_ + b) * H_;
    float acc = ys[(t * B_ + b) * H_ + j];
    acc += dot1024(hrow, wl0, sw);
    ys[(t * B_ + b) * H_ + j] = tanhf(acc);
    grid_barrier(bar, NBLK);
  }

  // ---- restage LDS with [W_ih1 | W_hh1] slice (16 x 2048)
  for (int i4 = tid * 4; i4 < 16 * 2048; i4 += 256 * 4) {
    int r = i4 >> 11, k = i4 & 2047;
    float4 v;
    if (k < 1024)
      v = *(const float4*)(Wih1 + (jg * 16 + r) * H_ + k);
    else
      v = *(const float4*)(Whh1 + (jg * 16 + r) * H_ + (k - 1024));
    *(float4*)(lds + r * 2048 + (k ^ ((r & 7) << 2))) = v;
  }
  __syncthreads();

  // ---- layer 1 recurrence (K = 2048 fused), h1 ping-pong
  const float* wi1 = lds + jl * 2048;
  const float* wh1 = wi1 + 1024;
  const float bs1 = bih1[j] + bhh1[j];
  for (int t = 0; t < T_; ++t) {
    const float* xrow = ys + (t * B_ + b) * H_;
    float acc = bs1 + dot1024(xrow, wi1, sw);
    if (t > 0) {
      const float* hr = ((t & 1) ? h1a : h1b) + b * H_;
      acc += dot1024(hr, wh1, sw);
    }
    float* hw = (t & 1) ? h1b : h1a;
    hw[b * H_ + j] = tanhf(acc);
    grid_barrier(bar, NBLK);
  }

  // ---- final linear + sigmoid: out[64][128]
  if (blk < 32) {
    const int o = tid & 127;
    const int bb = blk * 2 + (tid >> 7);
    const float* wrow = Wlin + o * (2 * H_);
    float acc = blin[o];
    acc += dot1024(ys + ((T_ - 1) * B_ + bb) * H_, wrow, 0);
    acc += dot1024(h1b + bb * H_, wrow + 1024, 0);
    out[bb * OUT_ + o] = 1.0f / (1.0f + expf(-acc));
  }
}

// ---------------------------------------------------------------------------
extern "C" void kernel_launch(void* const* d_in, const int* in_sizes, int n_in,
                              void* d_out, int out_size, void* d_ws, size_t ws_size,
                              hipStream_t stream) {
  const float* x    = (const float*)d_in[0];
  const float* Wih0 = (const float*)d_in[1];
  const float* Whh0 = (const float*)d_in[2];
  const float* bih0 = (const float*)d_in[3];
  const float* bhh0 = (const float*)d_in[4];
  const float* Wih1 = (const float*)d_in[5];
  const float* Whh1 = (const float*)d_in[6];
  const float* bih1 = (const float*)d_in[7];
  const float* bhh1 = (const float*)d_in[8];
  const float* Wlin = (const float*)d_in[9];
  const float* blin = (const float*)d_in[10];
  float* out = (float*)d_out;

  char* ws = (char*)d_ws;
  const size_t YS_BYTES = (size_t)T_ * B_ * H_ * 4;  // 128 MiB
  float* ys  = (float*)ws;
  float* h1a = (float*)(ws + YS_BYTES);
  float* h1b = (float*)(ws + YS_BYTES + (size_t)B_ * H_ * 4);
  unsigned* bar = (unsigned*)(ws + YS_BYTES + 2 * (size_t)B_ * H_ * 4);

  hipMemsetAsync(bar, 0, 256, stream);

  xw0_gemm<<<dim3(16, T_), 256, 0, stream>>>(x, Wih0, bih0, bhh0, ys);

  const int dyn_lds = 16 * 2048 * 4;  // 128 KiB
  hipFuncSetAttribute((const void*)rnn_seq, hipFuncAttributeMaxDynamicSharedMemorySize,
                      dyn_lds);
  void* args[] = {&Whh0, &Wih1, &Whh1, &bih1, &bhh1, &Wlin,
                  &blin, &ys,   &h1a,  &h1b,  &bar,  &out};
  hipLaunchCooperativeKernel((const void*)rnn_seq, dim3(NBLK), dim3(256), args, dyn_lds,
                             stream);
}

// Round 3
// 9095.429 us; speedup vs baseline: 4.1177x; 4.1177x over previous
//
#include <hip/hip_runtime.h>

// Problem constants: B=64, T=512, IN=256, H=1024, L=2, OUT=128
#define B_ 64
#define T_ 512
#define IN_ 256
#define H_ 1024
#define OUT_ 128
#define NBLK 256

typedef __attribute__((ext_vector_type(4))) float f32x4;
typedef __attribute__((ext_vector_type(8))) short s16x8;
typedef __attribute__((ext_vector_type(4))) short s16x4;
typedef unsigned short u16;

// fp32 -> bf16 RNE
__device__ __forceinline__ u16 f2bf(float f) {
  union { float f; unsigned u; } v; v.f = f;
  unsigned r = v.u + 0x7fffu + ((v.u >> 16) & 1u);
  return (u16)(r >> 16);
}
__device__ __forceinline__ float bf2f(u16 h) {
  union { unsigned u; float f; } v; v.u = ((unsigned)h) << 16;
  return v.f;
}
__device__ __forceinline__ s16x8 cvt8(const float* __restrict__ p) {
  float4 a = *(const float4*)p;
  float4 b = *(const float4*)(p + 4);
  s16x8 r;
  r[0] = (short)f2bf(a.x); r[1] = (short)f2bf(a.y);
  r[2] = (short)f2bf(a.z); r[3] = (short)f2bf(a.w);
  r[4] = (short)f2bf(b.x); r[5] = (short)f2bf(b.y);
  r[6] = (short)f2bf(b.z); r[7] = (short)f2bf(b.w);
  return r;
}

// Grid barrier (validated round 1: absmax 0.0 across 1024 steps).
__device__ __forceinline__ void grid_barrier(unsigned* bar, unsigned nblk) {
  __syncthreads();
  if (threadIdx.x == 0) {
    __builtin_amdgcn_fence(__ATOMIC_RELEASE, "agent");
    unsigned g = __hip_atomic_load(bar + 1, __ATOMIC_RELAXED, __HIP_MEMORY_SCOPE_AGENT);
    unsigned arrived =
        __hip_atomic_fetch_add(bar, 1u, __ATOMIC_RELAXED, __HIP_MEMORY_SCOPE_AGENT) + 1u;
    if (arrived == nblk) {
      __hip_atomic_store(bar, 0u, __ATOMIC_RELAXED, __HIP_MEMORY_SCOPE_AGENT);
      __hip_atomic_fetch_add(bar + 1, 1u, __ATOMIC_RELEASE, __HIP_MEMORY_SCOPE_AGENT);
    } else {
      while (__hip_atomic_load(bar + 1, __ATOMIC_RELAXED, __HIP_MEMORY_SCOPE_AGENT) == g) {
        __builtin_amdgcn_s_sleep(1);
      }
    }
    __builtin_amdgcn_fence(__ATOMIC_ACQUIRE, "agent");
  }
  __syncthreads();
}

// ---------------------------------------------------------------------------
// x [B][T][IN] fp32 -> xbf [T*B][IN] bf16 (transposed to step-major rows)
// 8192 blocks x 256 threads, 4 elems/thread.
// ---------------------------------------------------------------------------
__global__ __launch_bounds__(256) void cvt_x(const float* __restrict__ x,
                                             u16* __restrict__ xbf) {
  int i4 = blockIdx.x * 256 + threadIdx.x;  // 0 .. 2097151
  int r = i4 >> 6;                          // output row (t*64+b), 64 chunks/row
  int kc = (i4 & 63) * 4;
  int t = r >> 6, b = r & 63;
  float4 v = *(const float4*)(x + ((size_t)b * T_ + t) * IN_ + kc);
  s16x4 o;
  o[0] = (short)f2bf(v.x); o[1] = (short)f2bf(v.y);
  o[2] = (short)f2bf(v.z); o[3] = (short)f2bf(v.w);
  *(s16x4*)(xbf + (size_t)r * IN_ + kc) = o;
}

// W_ih0 [H][IN] fp32 -> bf16 (262144 elems). 256 blocks x 256 thr x 4.
__global__ __launch_bounds__(256) void cvt_w(const float* __restrict__ w,
                                             u16* __restrict__ wbf) {
  int i = blockIdx.x * 256 + threadIdx.x;
  float4 v = *(const float4*)(w + (size_t)i * 4);
  s16x4 o;
  o[0] = (short)f2bf(v.x); o[1] = (short)f2bf(v.y);
  o[2] = (short)f2bf(v.z); o[3] = (short)f2bf(v.w);
  *(s16x4*)(wbf + (size_t)i * 4) = o;
}

// ---------------------------------------------------------------------------
// xw0[r=t*64+b][j] = x_row[r] @ W_ih0^T + (b_ih0 + b_hh0), stored bf16.
// MFMA 16x16x32. Block tile [64 r x 64 j], 4 waves (wave w -> 16 rows, 4 j-tiles).
// grid (16 jg, 512 rg). W staged bf16 in LDS with XOR swizzle.
// ---------------------------------------------------------------------------
__global__ __launch_bounds__(256) void xw0_mfma(const u16* __restrict__ xbf,
                                                const u16* __restrict__ w0bf,
                                                const float* __restrict__ bih,
                                                const float* __restrict__ bhh,
                                                u16* __restrict__ xw0) {
  __shared__ char ldsW[64 * 512];  // 64 j rows x 256 k bf16, rowBytes=512
  const int tid = threadIdx.x;
  const int j0 = blockIdx.x * 64;
  const int r0 = blockIdx.y * 64;

  // stage W slice (64 x 256) bf16 -> LDS, 16B chunks, swizzled
  for (int c = tid; c < 64 * 32; c += 256) {
    int r = c >> 5, kc = c & 31;
    s16x8 w = *(const s16x8*)(w0bf + (size_t)(j0 + r) * IN_ + kc * 8);
    *(s16x8*)(ldsW + r * 512 + ((kc * 16) ^ ((r & 7) << 4))) = w;
  }
  __syncthreads();

  const int wv = tid >> 6, lane = tid & 63;
  const int col = lane & 15, kg = lane >> 4;
  const int rr = r0 + wv * 16 + col;  // A row (m = lane&15)
  const u16* aRow = xbf + (size_t)rr * IN_ + kg * 8;

  f32x4 acc[4] = {};
#pragma unroll
  for (int k0 = 0; k0 < IN_; k0 += 32) {
    s16x8 a = *(const s16x8*)(aRow + k0);
#pragma unroll
    for (int n = 0; n < 4; ++n) {
      int jr = n * 16 + col;
      s16x8 b = *(const s16x8*)(ldsW + jr * 512 + ((((k0 + kg * 8) << 1)) ^ ((jr & 7) << 4)));
      acc[n] = __builtin_amdgcn_mfma_f32_16x16x32_bf16(a, b, acc[n], 0, 0, 0);
    }
  }
#pragma unroll
  for (int n = 0; n < 4; ++n) {
    int j = j0 + n * 16 + col;
    float bs = bih[j] + bhh[j];
#pragma unroll
    for (int q = 0; q < 4; ++q) {
      int r = r0 + wv * 16 + kg * 4 + q;  // D row = (lane>>4)*4+q
      xw0[(size_t)r * H_ + j] = f2bf(acc[n][q] + bs);
    }
  }
}

// ---------------------------------------------------------------------------
// Persistent cooperative kernel. 256 blocks x 128 threads (2 waves).
// Block (jg=blk&63, bg=blk>>6) owns output tile [16b x 16j] of both layers.
//   wave 0, step s in [0,512): ys0[s] = tanh(xw0[s] + ys0[s-1] @ Whh0^T)
//   wave 1, step s in [1,512]: t1=s-1: h1[t1] = tanh(b1 + ys0[t1]@Wih1^T
//                                                    + h1[t1-1]@Whh1^T)
// One grid barrier per step (513 total), layers pipelined.
// LDS: W0 slice 16x1024 bf16 (32KB) + W1 slice 16x2048 bf16 (64KB), swizzled.
// ---------------------------------------------------------------------------
__global__ __launch_bounds__(128, 1) void rnn_seq(
    const float* __restrict__ Whh0, const float* __restrict__ Wih1,
    const float* __restrict__ Whh1, const float* __restrict__ bih1,
    const float* __restrict__ bhh1, const float* __restrict__ Wlin,
    const float* __restrict__ blin, const u16* __restrict__ xw0bf,
    u16* __restrict__ ys0, u16* __restrict__ h1a, u16* __restrict__ h1b,
    unsigned* __restrict__ bar, float* __restrict__ out) {
  extern __shared__ char lds[];  // [0,32768): W0  [32768,98304): W1
  char* ldsW0 = lds;
  char* ldsW1 = lds + 32768;
  const int tid = threadIdx.x;
  const int blk = blockIdx.x;
  const int jg = blk & 63, bg = blk >> 6;
  const int j0 = jg * 16, b0 = bg * 16;
  const int wv = tid >> 6, lane = tid & 63;
  const int col = lane & 15, kg = lane >> 4;
  const int sw = (col & 7) << 4;

  // stage W0 (16 x 1024 bf16, rowBytes 2048), fp32->bf16, swizzled
  for (int c = tid; c < 16 * 128; c += 128) {
    int r = c >> 7, kc = c & 127;
    s16x8 w = cvt8(Whh0 + (size_t)(j0 + r) * H_ + kc * 8);
    *(s16x8*)(ldsW0 + r * 2048 + ((kc * 16) ^ ((r & 7) << 4))) = w;
  }
  // stage W1 (16 x 2048 bf16, rowBytes 4096): [0,1024)=Wih1, [1024,2048)=Whh1
  for (int c = tid; c < 16 * 256; c += 128) {
    int r = c >> 8, kc = c & 255;
    const float* src = (kc < 128) ? (Wih1 + (size_t)(j0 + r) * H_ + kc * 8)
                                  : (Whh1 + (size_t)(j0 + r) * H_ + (kc - 128) * 8);
    s16x8 w = cvt8(src);
    *(s16x8*)(ldsW1 + r * 4096 + ((kc * 16) ^ ((r & 7) << 4))) = w;
  }
  __syncthreads();

  const float bias1 = bih1[j0 + col] + bhh1[j0 + col];

  for (int s = 0; s <= T_; ++s) {
    if (wv == 0) {
      if (s < T_) {
        // prefetch xw0 additive tile (independent of MFMA loop)
        const u16* xwp = xw0bf + (size_t)s * (B_ * H_) + (size_t)(b0 + kg * 4) * H_ + j0 + col;
        u16 xv0 = xwp[0], xv1 = xwp[H_], xv2 = xwp[2 * H_], xv3 = xwp[3 * H_];
        f32x4 acc = {};
        if (s > 0) {
          const u16* aRow = ys0 + (size_t)(s - 1) * (B_ * H_) + (size_t)(b0 + col) * H_ + kg * 8;
          const char* bB = ldsW0 + col * 2048;
#pragma unroll 8
          for (int k0 = 0; k0 < H_; k0 += 32) {
            s16x8 a = *(const s16x8*)(aRow + k0);
            s16x8 b = *(const s16x8*)(bB + (((k0 + kg * 8) << 1) ^ sw));
            acc = __builtin_amdgcn_mfma_f32_16x16x32_bf16(a, b, acc, 0, 0, 0);
          }
        }
        u16* ysC = ys0 + (size_t)s * (B_ * H_);
        ysC[(size_t)(b0 + kg * 4 + 0) * H_ + j0 + col] = f2bf(tanhf(acc[0] + bf2f(xv0)));
        ysC[(size_t)(b0 + kg * 4 + 1) * H_ + j0 + col] = f2bf(tanhf(acc[1] + bf2f(xv1)));
        ysC[(size_t)(b0 + kg * 4 + 2) * H_ + j0 + col] = f2bf(tanhf(acc[2] + bf2f(xv2)));
        ysC[(size_t)(b0 + kg * 4 + 3) * H_ + j0 + col] = f2bf(tanhf(acc[3] + bf2f(xv3)));
      }
    } else {
      if (s >= 1) {
        const int t1 = s - 1;
        u16* h1c = (t1 & 1) ? h1b : h1a;
        const u16* h1p = (t1 & 1) ? h1a : h1b;
        f32x4 acc = {};
        const char* bB = ldsW1 + col * 4096;
        const u16* a1 = ys0 + (size_t)t1 * (B_ * H_) + (size_t)(b0 + col) * H_ + kg * 8;
#pragma unroll 8
        for (int k0 = 0; k0 < H_; k0 += 32) {
          s16x8 a = *(const s16x8*)(a1 + k0);
          s16x8 b = *(const s16x8*)(bB + (((k0 + kg * 8) << 1) ^ sw));
          acc = __builtin_amdgcn_mfma_f32_16x16x32_bf16(a, b, acc, 0, 0, 0);
        }
        if (t1 > 0) {
          const u16* a2 = h1p + (size_t)(b0 + col) * H_ + kg * 8;
#pragma unroll 8
          for (int k0 = 0; k0 < H_; k0 += 32) {
            s16x8 a = *(const s16x8*)(a2 + k0);
            s16x8 b = *(const s16x8*)(bB + ((2048 + ((k0 + kg * 8) << 1)) ^ sw));
            acc = __builtin_amdgcn_mfma_f32_16x16x32_bf16(a, b, acc, 0, 0, 0);
          }
        }
        h1c[(size_t)(b0 + kg * 4 + 0) * H_ + j0 + col] = f2bf(tanhf(acc[0] + bias1));
        h1c[(size_t)(b0 + kg * 4 + 1) * H_ + j0 + col] = f2bf(tanhf(acc[1] + bias1));
        h1c[(size_t)(b0 + kg * 4 + 2) * H_ + j0 + col] = f2bf(tanhf(acc[2] + bias1));
        h1c[(size_t)(b0 + kg * 4 + 3) * H_ + j0 + col] = f2bf(tanhf(acc[3] + bias1));
      }
    }
    grid_barrier(bar, NBLK);
  }

  // ---- final linear + sigmoid: out[64][128], blocks 0..63 (b = blk, o = tid)
  if (blk < B_) {
    const int o = tid;  // 0..127
    const u16* hA = ys0 + (size_t)(T_ - 1) * (B_ * H_) + (size_t)blk * H_;
    const u16* hB = h1b + (size_t)blk * H_;  // t=511 odd -> h1b
    const float* wr = Wlin + (size_t)o * (2 * H_);
    float acc = blin[o];
#pragma unroll 4
    for (int k = 0; k < H_; k += 8) {
      s16x8 h = *(const s16x8*)(hA + k);
      float4 w0 = *(const float4*)(wr + k);
      float4 w1 = *(const float4*)(wr + k + 4);
      acc += bf2f((u16)h[0]) * w0.x + bf2f((u16)h[1]) * w0.y +
             bf2f((u16)h[2]) * w0.z + bf2f((u16)h[3]) * w0.w +
             bf2f((u16)h[4]) * w1.x + bf2f((u16)h[5]) * w1.y +
             bf2f((u16)h[6]) * w1.z + bf2f((u16)h[7]) * w1.w;
    }
#pragma unroll 4
    for (int k = 0; k < H_; k += 8) {
      s16x8 h = *(const s16x8*)(hB + k);
      float4 w0 = *(const float4*)(wr + H_ + k);
      float4 w1 = *(const float4*)(wr + H_ + k + 4);
      acc += bf2f((u16)h[0]) * w0.x + bf2f((u16)h[1]) * w0.y +
             bf2f((u16)h[2]) * w0.z + bf2f((u16)h[3]) * w0.w +
             bf2f((u16)h[4]) * w1.x + bf2f((u16)h[5]) * w1.y +
             bf2f((u16)h[6]) * w1.z + bf2f((u16)h[7]) * w1.w;
    }
    out[blk * OUT_ + o] = 1.0f / (1.0f + expf(-acc));
  }
}

// ---------------------------------------------------------------------------
extern "C" void kernel_launch(void* const* d_in, const int* in_sizes, int n_in,
                              void* d_out, int out_size, void* d_ws, size_t ws_size,
                              hipStream_t stream) {
  const float* x    = (const float*)d_in[0];
  const float* Wih0 = (const float*)d_in[1];
  const float* Whh0 = (const float*)d_in[2];
  const float* bih0 = (const float*)d_in[3];
  const float* bhh0 = (const float*)d_in[4];
  const float* Wih1 = (const float*)d_in[5];
  const float* Whh1 = (const float*)d_in[6];
  const float* bih1 = (const float*)d_in[7];
  const float* bhh1 = (const float*)d_in[8];
  const float* Wlin = (const float*)d_in[9];
  const float* blin = (const float*)d_in[10];
  float* out = (float*)d_out;

  char* ws = (char*)d_ws;
  const size_t TBH = (size_t)T_ * B_ * H_;  // 33,554,432 elems
  u16* xw0bf = (u16*)ws;                    // 64 MB
  u16* ys0   = (u16*)(ws + TBH * 2);        // 64 MB
  // xbf (16MB) + w0bf (0.5MB) alias the ys0 region: both are dead before
  // rnn_seq writes ys0 (stream-ordered), keeping total ws <= round-1 footprint.
  u16* xbf  = ys0;
  u16* w0bf = ys0 + (size_t)T_ * B_ * IN_;  // +16 MB
  u16* h1a  = (u16*)(ws + 2 * TBH * 2);     // 128 KB
  u16* h1b  = h1a + B_ * H_;                // 128 KB
  unsigned* bar = (unsigned*)(h1b + B_ * H_);

  hipMemsetAsync(bar, 0, 256, stream);

  cvt_x<<<8192, 256, 0, stream>>>(x, xbf);
  cvt_w<<<256, 256, 0, stream>>>(Wih0, w0bf);
  xw0_mfma<<<dim3(16, 512), 256, 0, stream>>>(xbf, w0bf, bih0, bhh0, xw0bf);

  const int dyn_lds = 98304;  // 32KB W0 + 64KB W1
  hipFuncSetAttribute((const void*)rnn_seq, hipFuncAttributeMaxDynamicSharedMemorySize,
                      dyn_lds);
  void* args[] = {&Whh0, &Wih1, &Whh1, &bih1, &bhh1, &Wlin, &blin,
                  &xw0bf, &ys0, &h1a, &h1b, &bar, &out};
  hipLaunchCooperativeKernel((const void*)rnn_seq, dim3(NBLK), dim3(128), args, dyn_lds,
                             stream);
}

// Round 4
// 7950.828 us; speedup vs baseline: 4.7104x; 1.1440x over previous
//
#include <hip/hip_runtime.h>

// Problem constants: B=64, T=512, IN=256, H=1024, L=2, OUT=128
#define B_ 64
#define T_ 512
#define IN_ 256
#define H_ 1024
#define OUT_ 128
#define NBLK 64
#define NTHR 512

typedef __attribute__((ext_vector_type(4))) float f32x4;
typedef __attribute__((ext_vector_type(8))) short s16x8;
typedef __attribute__((ext_vector_type(4))) short s16x4;
typedef unsigned short u16;

// fp32 -> bf16 RNE
__device__ __forceinline__ u16 f2bf(float f) {
  union { float f; unsigned u; } v; v.f = f;
  unsigned r = v.u + 0x7fffu + ((v.u >> 16) & 1u);
  return (u16)(r >> 16);
}
__device__ __forceinline__ float bf2f(u16 h) {
  union { unsigned u; float f; } v; v.u = ((unsigned)h) << 16;
  return v.f;
}
__device__ __forceinline__ s16x8 cvt8(const float* __restrict__ p) {
  float4 a = *(const float4*)p;
  float4 b = *(const float4*)(p + 4);
  s16x8 r;
  r[0] = (short)f2bf(a.x); r[1] = (short)f2bf(a.y);
  r[2] = (short)f2bf(a.z); r[3] = (short)f2bf(a.w);
  r[4] = (short)f2bf(b.x); r[5] = (short)f2bf(b.y);
  r[6] = (short)f2bf(b.z); r[7] = (short)f2bf(b.w);
  return r;
}

// Write-through 2B store to the coherence point (MALL): leaves no dirty L2
// line behind, so the grid barrier needs NO buffer_wbl2 release fence.
__device__ __forceinline__ void store_wt_u16(u16* p, u16 v) {
  unsigned d = v;
  asm volatile("global_store_short %0, %1, off sc0 sc1" :: "v"(p), "v"(d) : "memory");
}

// Grid barrier, write-through protocol:
//   release = s_waitcnt vmcnt(0) (caller) — WT stores are at MALL when retired
//   arrival/poll = relaxed agent atomics (sc1, bypass local caches)
//   acquire = fence(acquire) -> buffer_inv (clean-L2 tag invalidate, cheap)
__device__ __forceinline__ void grid_barrier_wt(unsigned* bar, unsigned nblk) {
  __syncthreads();
  if (threadIdx.x == 0) {
    unsigned g = __hip_atomic_load(bar + 1, __ATOMIC_RELAXED, __HIP_MEMORY_SCOPE_AGENT);
    unsigned arrived =
        __hip_atomic_fetch_add(bar, 1u, __ATOMIC_RELAXED, __HIP_MEMORY_SCOPE_AGENT) + 1u;
    if (arrived == nblk) {
      __hip_atomic_store(bar, 0u, __ATOMIC_RELAXED, __HIP_MEMORY_SCOPE_AGENT);
      __hip_atomic_fetch_add(bar + 1, 1u, __ATOMIC_RELAXED, __HIP_MEMORY_SCOPE_AGENT);
    } else {
      while (__hip_atomic_load(bar + 1, __ATOMIC_RELAXED, __HIP_MEMORY_SCOPE_AGENT) == g) {
        __builtin_amdgcn_s_sleep(1);
      }
    }
    __builtin_amdgcn_fence(__ATOMIC_ACQUIRE, "agent");
  }
  __syncthreads();
}

// ---------------------------------------------------------------------------
// x [B][T][IN] fp32 -> xbf [T*B][IN] bf16 (step-major rows)
// ---------------------------------------------------------------------------
__global__ __launch_bounds__(256) void cvt_x(const float* __restrict__ x,
                                             u16* __restrict__ xbf) {
  int i4 = blockIdx.x * 256 + threadIdx.x;
  int r = i4 >> 6;
  int kc = (i4 & 63) * 4;
  int t = r >> 6, b = r & 63;
  float4 v = *(const float4*)(x + ((size_t)b * T_ + t) * IN_ + kc);
  s16x4 o;
  o[0] = (short)f2bf(v.x); o[1] = (short)f2bf(v.y);
  o[2] = (short)f2bf(v.z); o[3] = (short)f2bf(v.w);
  *(s16x4*)(xbf + (size_t)r * IN_ + kc) = o;
}

__global__ __launch_bounds__(256) void cvt_w(const float* __restrict__ w,
                                             u16* __restrict__ wbf) {
  int i = blockIdx.x * 256 + threadIdx.x;
  float4 v = *(const float4*)(w + (size_t)i * 4);
  s16x4 o;
  o[0] = (short)f2bf(v.x); o[1] = (short)f2bf(v.y);
  o[2] = (short)f2bf(v.z); o[3] = (short)f2bf(v.w);
  *(s16x4*)(wbf + (size_t)i * 4) = o;
}

// ---------------------------------------------------------------------------
// xw0[r=t*64+b][j] = x_row[r] @ W_ih0^T + (b_ih0 + b_hh0), stored bf16.
// (unchanged from round 3 — validated)
// ---------------------------------------------------------------------------
__global__ __launch_bounds__(256) void xw0_mfma(const u16* __restrict__ xbf,
                                                const u16* __restrict__ w0bf,
                                                const float* __restrict__ bih,
                                                const float* __restrict__ bhh,
                                                u16* __restrict__ xw0) {
  __shared__ char ldsW[64 * 512];
  const int tid = threadIdx.x;
  const int j0 = blockIdx.x * 64;
  const int r0 = blockIdx.y * 64;

  for (int c = tid; c < 64 * 32; c += 256) {
    int r = c >> 5, kc = c & 31;
    s16x8 w = *(const s16x8*)(w0bf + (size_t)(j0 + r) * IN_ + kc * 8);
    *(s16x8*)(ldsW + r * 512 + ((kc * 16) ^ ((r & 7) << 4))) = w;
  }
  __syncthreads();

  const int wv = tid >> 6, lane = tid & 63;
  const int col = lane & 15, kg = lane >> 4;
  const int rr = r0 + wv * 16 + col;
  const u16* aRow = xbf + (size_t)rr * IN_ + kg * 8;

  f32x4 acc[4] = {};
#pragma unroll
  for (int k0 = 0; k0 < IN_; k0 += 32) {
    s16x8 a = *(const s16x8*)(aRow + k0);
#pragma unroll
    for (int n = 0; n < 4; ++n) {
      int jr = n * 16 + col;
      s16x8 b = *(const s16x8*)(ldsW + jr * 512 + ((((k0 + kg * 8) << 1)) ^ ((jr & 7) << 4)));
      acc[n] = __builtin_amdgcn_mfma_f32_16x16x32_bf16(a, b, acc[n], 0, 0, 0);
    }
  }
#pragma unroll
  for (int n = 0; n < 4; ++n) {
    int j = j0 + n * 16 + col;
    float bs = bih[j] + bhh[j];
#pragma unroll
    for (int q = 0; q < 4; ++q) {
      int r = r0 + wv * 16 + kg * 4 + q;
      xw0[(size_t)r * H_ + j] = f2bf(acc[n][q] + bs);
    }
  }
}

// ---------------------------------------------------------------------------
// Persistent cooperative kernel. 64 blocks x 512 threads (8 waves).
// Block jg owns 16 j-cols of both layers; waves 0-3 = layer 0 (b-tile wv*16),
// waves 4-7 = layer 1 (b-tile (wv-4)*16, K=2048). Layers pipelined: at step s
// layer 0 writes ys0[s] while layer 1 consumes ys0[s-1]. One barrier per step.
// h/ys stores are write-through (sc0 sc1) -> barrier needs no L2 writeback.
// LDS: W0 16x1024 bf16 (32KB) + W1 16x2048 bf16 (64KB), XOR-swizzled.
// ---------------------------------------------------------------------------
__global__ __launch_bounds__(NTHR, 1) void rnn_seq(
    const float* __restrict__ Whh0, const float* __restrict__ Wih1,
    const float* __restrict__ Whh1, const float* __restrict__ bih1,
    const float* __restrict__ bhh1, const float* __restrict__ Wlin,
    const float* __restrict__ blin, const u16* __restrict__ xw0bf,
    u16* __restrict__ ys0, u16* __restrict__ h1a, u16* __restrict__ h1b,
    unsigned* __restrict__ bar, float* __restrict__ out) {
  extern __shared__ char lds[];
  char* ldsW0 = lds;           // 16 rows x 2048 B
  char* ldsW1 = lds + 32768;   // 16 rows x 4096 B
  const int tid = threadIdx.x;
  const int blk = blockIdx.x;  // jg 0..63
  const int j0 = blk * 16;
  const int wv = tid >> 6, lane = tid & 63;
  const int col = lane & 15, kg = lane >> 4;
  const int sw = (col & 7) << 4;
  const int b0 = (wv & 3) * 16;
  const bool isL1 = wv >= 4;

  // stage W0 slice (16 x 1024 bf16), fp32->bf16, swizzled
  for (int c = tid; c < 16 * 128; c += NTHR) {
    int r = c >> 7, kc = c & 127;
    s16x8 w = cvt8(Whh0 + (size_t)(j0 + r) * H_ + kc * 8);
    *(s16x8*)(ldsW0 + r * 2048 + ((kc * 16) ^ ((r & 7) << 4))) = w;
  }
  // stage W1 slice (16 x 2048 bf16): [0,1024)=Wih1, [1024,2048)=Whh1
  for (int c = tid; c < 16 * 256; c += NTHR) {
    int r = c >> 8, kc = c & 255;
    const float* src = (kc < 128) ? (Wih1 + (size_t)(j0 + r) * H_ + kc * 8)
                                  : (Whh1 + (size_t)(j0 + r) * H_ + (kc - 128) * 8);
    *(s16x8*)(ldsW1 + r * 4096 + ((kc * 16) ^ ((r & 7) << 4))) = cvt8(src);
  }
  __syncthreads();

  const float bias1 = bih1[j0 + col] + bhh1[j0 + col];

  for (int s = 0; s <= T_; ++s) {
    if (!isL1) {
      if (s < T_) {
        const u16* xwp =
            xw0bf + (size_t)s * (B_ * H_) + (size_t)(b0 + kg * 4) * H_ + j0 + col;
        u16 xv0 = xwp[0], xv1 = xwp[H_], xv2 = xwp[2 * H_], xv3 = xwp[3 * H_];
        f32x4 acc = {};
        if (s > 0) {
          const u16* aRow =
              ys0 + (size_t)(s - 1) * (B_ * H_) + (size_t)(b0 + col) * H_ + kg * 8;
          const char* bB = ldsW0 + col * 2048;
#pragma unroll 8
          for (int k0 = 0; k0 < H_; k0 += 32) {
            s16x8 a = *(const s16x8*)(aRow + k0);
            s16x8 b = *(const s16x8*)(bB + (((k0 + kg * 8) << 1) ^ sw));
            acc = __builtin_amdgcn_mfma_f32_16x16x32_bf16(a, b, acc, 0, 0, 0);
          }
        }
        u16* ysC = ys0 + (size_t)s * (B_ * H_) + (size_t)(b0 + kg * 4) * H_ + j0 + col;
        store_wt_u16(ysC + 0 * H_, f2bf(tanhf(acc[0] + bf2f(xv0))));
        store_wt_u16(ysC + 1 * H_, f2bf(tanhf(acc[1] + bf2f(xv1))));
        store_wt_u16(ysC + 2 * H_, f2bf(tanhf(acc[2] + bf2f(xv2))));
        store_wt_u16(ysC + 3 * H_, f2bf(tanhf(acc[3] + bf2f(xv3))));
      }
    } else {
      if (s >= 1) {
        const int t1 = s - 1;
        u16* h1c = (t1 & 1) ? h1b : h1a;
        const u16* h1p = (t1 & 1) ? h1a : h1b;
        f32x4 acc = {};
        const char* bB = ldsW1 + col * 4096;
        const u16* a1 =
            ys0 + (size_t)t1 * (B_ * H_) + (size_t)(b0 + col) * H_ + kg * 8;
#pragma unroll 8
        for (int k0 = 0; k0 < H_; k0 += 32) {
          s16x8 a = *(const s16x8*)(a1 + k0);
          s16x8 b = *(const s16x8*)(bB + (((k0 + kg * 8) << 1) ^ sw));
          acc = __builtin_amdgcn_mfma_f32_16x16x32_bf16(a, b, acc, 0, 0, 0);
        }
        if (t1 > 0) {
          const u16* a2 = h1p + (size_t)(b0 + col) * H_ + kg * 8;
#pragma unroll 8
          for (int k0 = 0; k0 < H_; k0 += 32) {
            s16x8 a = *(const s16x8*)(a2 + k0);
            s16x8 b = *(const s16x8*)(bB + ((2048 + ((k0 + kg * 8) << 1)) ^ sw));
            acc = __builtin_amdgcn_mfma_f32_16x16x32_bf16(a, b, acc, 0, 0, 0);
          }
        }
        u16* hc = h1c + (size_t)(b0 + kg * 4) * H_ + j0 + col;
        store_wt_u16(hc + 0 * H_, f2bf(tanhf(acc[0] + bias1)));
        store_wt_u16(hc + 1 * H_, f2bf(tanhf(acc[1] + bias1)));
        store_wt_u16(hc + 2 * H_, f2bf(tanhf(acc[2] + bias1)));
        store_wt_u16(hc + 3 * H_, f2bf(tanhf(acc[3] + bias1)));
      }
    }
    // release: drain write-through stores to the coherence point
    asm volatile("s_waitcnt vmcnt(0)" ::: "memory");
    grid_barrier_wt(bar, NBLK);
  }

  // ---- final linear + sigmoid: out[64][128], block b = blk, thread o = tid
  if (tid < OUT_) {
    const int o = tid;
    const u16* hA = ys0 + (size_t)(T_ - 1) * (B_ * H_) + (size_t)blk * H_;
    const u16* hB = h1b + (size_t)blk * H_;  // t=511 odd -> h1b
    const float* wr = Wlin + (size_t)o * (2 * H_);
    float acc = blin[o];
#pragma unroll 4
    for (int k = 0; k < H_; k += 8) {
      s16x8 h = *(const s16x8*)(hA + k);
      float4 w0 = *(const float4*)(wr + k);
      float4 w1 = *(const float4*)(wr + k + 4);
      acc += bf2f((u16)h[0]) * w0.x + bf2f((u16)h[1]) * w0.y +
             bf2f((u16)h[2]) * w0.z + bf2f((u16)h[3]) * w0.w +
             bf2f((u16)h[4]) * w1.x + bf2f((u16)h[5]) * w1.y +
             bf2f((u16)h[6]) * w1.z + bf2f((u16)h[7]) * w1.w;
    }
#pragma unroll 4
    for (int k = 0; k < H_; k += 8) {
      s16x8 h = *(const s16x8*)(hB + k);
      float4 w0 = *(const float4*)(wr + H_ + k);
      float4 w1 = *(const float4*)(wr + H_ + k + 4);
      acc += bf2f((u16)h[0]) * w0.x + bf2f((u16)h[1]) * w0.y +
             bf2f((u16)h[2]) * w0.z + bf2f((u16)h[3]) * w0.w +
             bf2f((u16)h[4]) * w1.x + bf2f((u16)h[5]) * w1.y +
             bf2f((u16)h[6]) * w1.z + bf2f((u16)h[7]) * w1.w;
    }
    out[blk * OUT_ + o] = 1.0f / (1.0f + expf(-acc));
  }
}

// ---------------------------------------------------------------------------
extern "C" void kernel_launch(void* const* d_in, const int* in_sizes, int n_in,
                              void* d_out, int out_size, void* d_ws, size_t ws_size,
                              hipStream_t stream) {
  const float* x    = (const float*)d_in[0];
  const float* Wih0 = (const float*)d_in[1];
  const float* Whh0 = (const float*)d_in[2];
  const float* bih0 = (const float*)d_in[3];
  const float* bhh0 = (const float*)d_in[4];
  const float* Wih1 = (const float*)d_in[5];
  const float* Whh1 = (const float*)d_in[6];
  const float* bih1 = (const float*)d_in[7];
  const float* bhh1 = (const float*)d_in[8];
  const float* Wlin = (const float*)d_in[9];
  const float* blin = (const float*)d_in[10];
  float* out = (float*)d_out;

  char* ws = (char*)d_ws;
  const size_t TBH = (size_t)T_ * B_ * H_;
  u16* xw0bf = (u16*)ws;                    // 64 MB
  u16* ys0   = (u16*)(ws + TBH * 2);        // 64 MB
  u16* xbf  = ys0;                          // aliases (dead before rnn_seq)
  u16* w0bf = ys0 + (size_t)T_ * B_ * IN_;
  u16* h1a  = (u16*)(ws + 2 * TBH * 2);
  u16* h1b  = h1a + B_ * H_;
  unsigned* bar = (unsigned*)(h1b + B_ * H_);

  hipMemsetAsync(bar, 0, 256, stream);

  cvt_x<<<8192, 256, 0, stream>>>(x, xbf);
  cvt_w<<<256, 256, 0, stream>>>(Wih0, w0bf);
  xw0_mfma<<<dim3(16, 512), 256, 0, stream>>>(xbf, w0bf, bih0, bhh0, xw0bf);

  const int dyn_lds = 98304;  // 32KB W0 + 64KB W1
  hipFuncSetAttribute((const void*)rnn_seq, hipFuncAttributeMaxDynamicSharedMemorySize,
                      dyn_lds);
  void* args[] = {&Whh0, &Wih1, &Whh1, &bih1, &bhh1, &Wlin, &blin,
                  &xw0bf, &ys0, &h1a, &h1b, &bar, &out};
  hipLaunchCooperativeKernel((const void*)rnn_seq, dim3(NBLK), dim3(NTHR), args, dyn_lds,
                             stream);
}